// Round 8
// baseline (235.576 us; speedup 1.0000x reference)
//
#include <hip/hip_runtime.h>

#define N_HALF 8192
#define D 128
#define NBLK 2112

typedef float f32x4 __attribute__((ext_vector_type(4)));

// ws layout (4327428 B):
// [0,       2097152)  bfA  -- fp8 e4m3 of (-2*x), fragment-major kk-paired:
//                       frag(T,p,ni) @ ((T*2+p)*4+ni)*1024; lane l byte [l*16+h*8+j]
//                       = row T*64+ni*16+(l&15), k = (2p+h)*32+(l>>4)*8+j
// [2097152, 4194304)  bfB  -- fp8 e4m3 of (x), same layout
// [4194304, 4259840)  sq      (16384 f32)  -- exact fp32 |row|^2
// [4259840, 4292608)  U       (8192 f32)   -- rowsum_aa + rowsum_ab
// [4292608, 4325376)  V       (8192 f32)   -- colsum_ab + rowsum_bb
// [4325376, 4327424)  alignP  (512 f32)    -- per-a-block align partials
// [4327424, 4327428)  done    (1 u32)      -- band completion ticket
#define OFF_B    2097152
#define OFF_SQ   4194304
#define OFF_U    4259840
#define OFF_V    4292608
#define OFF_AL   4325376
#define OFF_DONE 4327424

union Frag { uint4 u; long h[2]; };

__device__ __forceinline__ unsigned short f2bf(float f) {
    unsigned int u = __float_as_uint(f);
    u += 0x7fffu + ((u >> 16) & 1u);   // round-to-nearest-even
    return (unsigned short)(u >> 16);
}

__device__ __forceinline__ void async_cp16(const void* g, void* l) {
    __builtin_amdgcn_global_load_lds(
        (const __attribute__((address_space(1))) void*)g,
        (__attribute__((address_space(3))) void*)l, 16, 0, 0);
}

// ---- prep: 1024 blocks, one 16-row single-side slice each. Exact fp32 norms +
// diag-align; emits fp8 fragments: bfA = fp8(-2x), bfB = fp8(x) (kk-paired).
__global__ __launch_bounds__(256) void prep_kernel(
    const float* __restrict__ feats, unsigned char* __restrict__ bfA,
    unsigned char* __restrict__ bfB,
    float* __restrict__ sq, float* __restrict__ U, float* __restrict__ V,
    float* __restrict__ alignP, unsigned int* __restrict__ done)
{
    __shared__ float ld[16 * 132];
    __shared__ float alg[16];

    const int side = blockIdx.x >> 9;          // 0 = a, 1 = b
    const int idx = blockIdx.x & 511;
    const int g0 = idx * 16;                   // first row within the half
    const int R = side * N_HALF + g0;          // global feature-row base
    const int t = threadIdx.x;

    // stage 16 rows (8 KB) coalesced
#pragma unroll
    for (int it = 0; it < 2; ++it) {
        int i4 = it * 256 + t;                 // 0..511 float4 slots
        int row = i4 >> 5, c4 = i4 & 31;
        *(float4*)&ld[row * 132 + c4 * 4] =
            *(const float4*)(feats + (size_t)(R + row) * D + c4 * 4);
    }
    if (t < 16) { if (side == 0) U[g0 + t] = 0.f; else V[g0 + t] = 0.f; }
    if (blockIdx.x == 0 && t == 16) *done = 0u;   // reset band ticket each iter
    __syncthreads();

    const int r = t >> 4;                      // row 0..15 (16 threads/row)
    const int c = t & 15;
    float sa = 0.f;
#pragma unroll
    for (int k = 0; k < 8; k += 4) {
        float4 v = *(const float4*)&ld[r * 132 + c * 8 + k];
        sa += v.x * v.x + v.y * v.y + v.z * v.z + v.w * v.w;
    }
    sa += __shfl_xor(sa, 1);
    sa += __shfl_xor(sa, 2);
    sa += __shfl_xor(sa, 4);
    sa += __shfl_xor(sa, 8);
    if (c == 0) sq[R + r] = sa;

    if (side == 0) {   // exact diag alignment: dot(a_r, b_r) + local b-norm
        float dt = 0.f, sb = 0.f;
        const float* brow = feats + (size_t)(N_HALF + g0 + r) * D + c * 8;
#pragma unroll
        for (int k = 0; k < 8; k += 4) {
            float4 bv = *(const float4*)(brow + k);
            float4 av = *(const float4*)&ld[r * 132 + c * 8 + k];
            dt += av.x * bv.x + av.y * bv.y + av.z * bv.z + av.w * bv.w;
            sb += bv.x * bv.x + bv.y * bv.y + bv.z * bv.z + bv.w * bv.w;
        }
        dt += __shfl_xor(dt, 1); sb += __shfl_xor(sb, 1);
        dt += __shfl_xor(dt, 2); sb += __shfl_xor(sb, 2);
        dt += __shfl_xor(dt, 4); sb += __shfl_xor(sb, 4);
        dt += __shfl_xor(dt, 8); sb += __shfl_xor(sb, 8);
        if (c == 0) {
            float d2 = fmaxf(sa + sb - 2.0f * dt, 0.0f);
            alg[r] = -__logf(d2 + 1.0f);
        }
    }

    // fp8 fragment emission: (T = side*128+idx>>2, ni = idx&3); uint t of each
    // 1KB frag: l = t>>2, half = (t>>1)&1, j0 = (t&1)*4.
    const int l = t >> 2, half = (t >> 1) & 1, j0 = (t & 1) * 4;
    const int rloc = l & 15, quad = l >> 4;
    const size_t Tb = ((size_t)(side * 128 + (idx >> 2))) * 8 + (idx & 3);
#pragma unroll
    for (int p = 0; p < 2; ++p) {
        const int k = p * 64 + half * 32 + quad * 8 + j0;
        float4 v = *(const float4*)&ld[rloc * 132 + k];
        int ub = __builtin_amdgcn_cvt_pk_fp8_f32(v.x, v.y, 0, false);
        ub = __builtin_amdgcn_cvt_pk_fp8_f32(v.z, v.w, ub, true);
        int ua = __builtin_amdgcn_cvt_pk_fp8_f32(-2.f * v.x, -2.f * v.y, 0, false);
        ua = __builtin_amdgcn_cvt_pk_fp8_f32(-2.f * v.z, -2.f * v.w, ua, true);
        ((unsigned int*)bfA)[(Tb + p * 4) * 256 + t] = (unsigned int)ua;
        ((unsigned int*)bfB)[(Tb + p * 4) * 256 + t] = (unsigned int)ub;
    }
    if (side == 0) {
        __syncthreads();
        if (t == 0) {
            float s = 0.f;
#pragma unroll
            for (int rr = 0; rr < 16; ++rr) s += alg[rr];
            alignP[idx] = s;
        }
    }
}

// ---- band kernel, R8: exact R3 structure (confirmed 53 us champion: LDS DMA
// dbuf + counted-vmcnt barrier + LDS col partials + end-of-job flush;
// launch_bounds(256,4) -- R7 proved (256,6) spills), plus:
//  (a) conflict-free colP zeroing (lane*4 stride),
//  (b) TAIL FOLDED IN: after flushes, each block tickets `done`; the LAST
//      block reads U/V with device-scope atomic loads (same-kernel cross-XCD
//      atomics are not plain-load visible), sums logs + alignP, writes loss.
//      Removes the tail dispatch + one kernel boundary from the ~55us fixed
//      non-band overhead.
__global__ __launch_bounds__(256, 4) void band_kernel(
    const unsigned char* __restrict__ bfA, const unsigned char* __restrict__ bfB,
    const float* __restrict__ sq, float* __restrict__ U, float* __restrict__ V,
    const float* __restrict__ alignP, unsigned int* __restrict__ done,
    unsigned int* __restrict__ out)
{
    __shared__ unsigned char lB[2][8192];   // 2 x 8 KB B dbuf
    __shared__ float colP[4][512];          // per-wave col partials (8 KB)
    __shared__ unsigned int lastFlag;

    int kind, band, js;
    {
        int id = blockIdx.x;
        if (id < 1024) { kind = 0; band = id & 63; js = (id >> 6) * 8; }
        else {
            int t = id - 1024;
            kind = 1;
            if (t >= 544) { t -= 544; kind = 2; }
            int g = 0;
            while (t >= 4 * (16 - g)) { t -= 4 * (16 - g); ++g; }   // <=15 iters
            band = 4 * g + (t & 3);
            js = 8 * (g + (t >> 2));
        }
    }
    const int je = js + 8;
    const bool sym = (kind != 0);

    const int wave = threadIdx.x >> 6, lane = threadIdx.x & 63;
    const int l15 = lane & 15, quad = lane >> 4;

    const int T_Aw = (kind == 2 ? 128 : 0) + 2 * band + (wave >> 1);
    const int niA0 = (wave & 1) * 2;
    const int T_B0 = (kind == 1 ? 0 : 128);
    const int rowSqB = (kind == 2 ? N_HALF : 0);
    const int colSqB = (kind == 1 ? 0 : N_HALF);
    float* const rowDst = (kind == 2) ? V : U;
    float* const colDst = (kind == 1) ? U : V;
    const int wRow0 = band * 128 + wave * 32;

    // each wave zeroes ITS OWN colP region; lane*4 stride = 64 consecutive
    // float4 slots (fixes R3's 135K bank-conflict events)
    {
        float4 z = make_float4(0.f, 0.f, 0.f, 0.f);
        *(float4*)&colP[wave][lane * 4] = z;
        *(float4*)&colP[wave][256 + lane * 4] = z;
    }

    // A fragments (32 rows, pre-scaled -2 in fp8): af[mi][p], 2 kk per b128
    Frag af[2][2];
#pragma unroll
    for (int mi = 0; mi < 2; ++mi)
#pragma unroll
        for (int p = 0; p < 2; ++p)
            af[mi][p].u = *(const uint4*)(bfA +
                ((size_t)T_Aw * 8 + p * 4 + niA0 + mi) * 1024 + lane * 16);

    float2 rs2[4];
#pragma unroll
    for (int mi = 0; mi < 2; ++mi)
#pragma unroll
        for (int rh = 0; rh < 2; ++rh) {
            const float* p = sq + rowSqB + wRow0 + mi * 16 + quad * 4 + 2 * rh;
            rs2[mi * 2 + rh] = make_float2(p[0] + 1.0f, p[1] + 1.0f);
        }

    float2 rowAcc2[4];
#pragma unroll
    for (int x = 0; x < 4; ++x) rowAcc2[x] = make_float2(0.f, 0.f);

    // stage tile t (8 KB contiguous): wave copies 2KB via 2 x 1KB DMA instrs
    auto stage = [&](int t, int s) {
        const unsigned char* src = bfB + (size_t)(T_B0 + t) * 8192 + wave * 2048 + lane * 16;
        unsigned char* dst = &lB[s][wave * 2048];
        async_cp16(src, dst);
        async_cp16(src + 1024, dst + 1024);
    };

    stage(js, 0);
    __builtin_amdgcn_sched_barrier(0);         // pin: stage before csq loads
    float csqN[4];
#pragma unroll
    for (int ni = 0; ni < 4; ++ni)
        csqN[ni] = sq[colSqB + js * 64 + ni * 16 + l15];

    for (int t = js; t < je; ++t) {
        const int s = (t - js) & 1;
        // counted drain: everything except the 4 newest vmem ops (this iter's
        // csq prefetch) must land => guarantees stage(t) complete.
        asm volatile("s_waitcnt vmcnt(4)" ::: "memory");
        __builtin_amdgcn_s_barrier();
        if (t + 1 < je) stage(t + 1, s ^ 1);
        __builtin_amdgcn_sched_barrier(0);     // pin: stage above csq/compute

        const int jn = (t + 1 < je) ? t + 1 : t;
        float csq[4] = {csqN[0], csqN[1], csqN[2], csqN[3]};
#pragma unroll
        for (int ni = 0; ni < 4; ++ni)
            csqN[ni] = sq[colSqB + jn * 64 + ni * 16 + l15];

        if (sym && (t * 64 + 64) <= wRow0) continue;   // fully below diagonal

        // acc init = |a|^2 + |b|^2 + 1 (packed); MFMA adds -2*dot => acc = d2+1
        f32x4 acc[2][4];
#pragma unroll
        for (int mi = 0; mi < 2; ++mi)
#pragma unroll
            for (int ni = 0; ni < 4; ++ni) {
                acc[mi][ni][0] = rs2[mi * 2].x + csq[ni];
                acc[mi][ni][1] = rs2[mi * 2].y + csq[ni];
                acc[mi][ni][2] = rs2[mi * 2 + 1].x + csq[ni];
                acc[mi][ni][3] = rs2[mi * 2 + 1].y + csq[ni];
            }

#pragma unroll
        for (int p = 0; p < 2; ++p) {
            Frag bfr[4];
#pragma unroll
            for (int ni = 0; ni < 4; ++ni)
                bfr[ni].u = *(const uint4*)&lB[s][(p * 4 + ni) * 1024 + lane * 16];
#pragma unroll
            for (int h = 0; h < 2; ++h)
#pragma unroll
                for (int mi = 0; mi < 2; ++mi)
#pragma unroll
                    for (int ni = 0; ni < 4; ++ni)
                        acc[mi][ni] = __builtin_amdgcn_mfma_f32_16x16x32_fp8_fp8(
                            af[mi][p].h[h], bfr[ni].h[h], acc[mi][ni], 0, 0, 0);
        }

        const bool maskDiag = sym && (t * 64 < wRow0 + 32);
        float colv[4];
        if (!maskDiag) {
            // packed epilogue. No fmax clamp: off-diagonal d2 >= ~80 even with
            // fp8 quantization error, so acc = d2+1 is always >> 1 here.
            float2 cp[4];
#pragma unroll
            for (int ni = 0; ni < 4; ++ni) cp[ni] = make_float2(0.f, 0.f);
#pragma unroll
            for (int mi = 0; mi < 2; ++mi)
#pragma unroll
                for (int ni = 0; ni < 4; ++ni) {
                    float2 slo = make_float2(__builtin_amdgcn_rcpf(acc[mi][ni][0]),
                                             __builtin_amdgcn_rcpf(acc[mi][ni][1]));
                    float2 shi = make_float2(__builtin_amdgcn_rcpf(acc[mi][ni][2]),
                                             __builtin_amdgcn_rcpf(acc[mi][ni][3]));
                    rowAcc2[mi * 2].x += slo.x;     rowAcc2[mi * 2].y += slo.y;
                    rowAcc2[mi * 2 + 1].x += shi.x; rowAcc2[mi * 2 + 1].y += shi.y;
                    cp[ni].x += slo.x + shi.x;
                    cp[ni].y += slo.y + shi.y;
                }
#pragma unroll
            for (int ni = 0; ni < 4; ++ni) colv[ni] = cp[ni].x + cp[ni].y;
        } else {
            // scalar masked path (diagonal-overlap tiles only) — keeps clamp
            float colPart[4] = {0.f, 0.f, 0.f, 0.f};
#pragma unroll
            for (int mi = 0; mi < 2; ++mi)
#pragma unroll
                for (int ni = 0; ni < 4; ++ni)
#pragma unroll
                    for (int r = 0; r < 4; ++r) {
                        float sim = __builtin_amdgcn_rcpf(fmaxf(acc[mi][ni][r], 1.0f));
                        if ((t * 64 + ni * 16 + l15) <= (wRow0 + mi * 16 + quad * 4 + r))
                            sim = 0.0f;   // strict upper only
                        if (r & 1) rowAcc2[mi * 2 + (r >> 1)].y += sim;
                        else       rowAcc2[mi * 2 + (r >> 1)].x += sim;
                        colPart[ni] += sim;
                    }
#pragma unroll
            for (int ni = 0; ni < 4; ++ni) colv[ni] = colPart[ni];
        }

        // col partials -> LDS (plain ds_write, one slot per (wave,step,ni,l15))
#pragma unroll
        for (int ni = 0; ni < 4; ++ni) {
            float cv = colv[ni];
            cv += __shfl_xor(cv, 16);
            cv += __shfl_xor(cv, 32);
            if (quad == 0) colP[wave][(t - js) * 64 + ni * 16 + l15] = cv;
        }
    }

    // end-of-job col flush: cross-wave reduce in LDS, <=512 atomics per block
    __syncthreads();
    {
        int c = threadIdx.x;
#pragma unroll
        for (int rep = 0; rep < 2; ++rep, c += 256) {
            float sv = colP[0][c] + colP[1][c] + colP[2][c] + colP[3][c];
            if (sv != 0.f) atomicAdd(&colDst[js * 64 + c], sv);
        }
    }

    // row flush: reduce over 16 l15 lanes, one atomic per row, once per job
#pragma unroll
    for (int x = 0; x < 8; ++x) {
        float v = (x & 1) ? rowAcc2[x >> 1].y : rowAcc2[x >> 1].x;
        v += __shfl_xor(v, 1);
        v += __shfl_xor(v, 2);
        v += __shfl_xor(v, 4);
        v += __shfl_xor(v, 8);
        if (l15 == 0)
            atomicAdd(&rowDst[wRow0 + (x >> 2) * 16 + quad * 4 + (x & 3)], v);
    }

    // ---- folded tail: last block to finish reduces U,V,alignP -> loss
    __threadfence();                             // release our U/V atomics
    if (threadIdx.x == 0)
        lastFlag = (atomicAdd(done, 1u) == (unsigned)(NBLK - 1)) ? 1u : 0u;
    __syncthreads();
    if (!lastFlag) return;
    __threadfence();                             // acquire side

    const int tid = threadIdx.x;
    float s = 0.f;
#pragma unroll
    for (int k = 0; k < 32; ++k) {               // coalesced: tid + 256*k
        float u = __hip_atomic_load(&U[tid + 256 * k], __ATOMIC_RELAXED,
                                    __HIP_MEMORY_SCOPE_AGENT);
        float v = __hip_atomic_load(&V[tid + 256 * k], __ATOMIC_RELAXED,
                                    __HIP_MEMORY_SCOPE_AGENT);
        s += __logf(u) + __logf(v);
    }
    float a = alignP[tid & 255] * 0.f + alignP[tid] + alignP[tid + 256];
    float m = a - 0.5f * s;
#pragma unroll
    for (int off = 32; off; off >>= 1) m += __shfl_xor(m, off);
    __syncthreads();                             // colP free for reuse
    if (lane == 0) colP[0][wave] = m;
    __syncthreads();
    if (tid == 0) {
        float tot = colP[0][0] + colP[0][1] + colP[0][2] + colP[0][3];
        float loss = -(tot / (float)N_HALF);
        unsigned int h = (unsigned int)f2bf(loss);
        out[0] = (h << 16) | h;   // fp32 reader: loss @ bf16 precision; bf16 reader: h
    }
}

extern "C" void kernel_launch(void* const* d_in, const int* in_sizes, int n_in,
                              void* d_out, int out_size, void* d_ws, size_t ws_size,
                              hipStream_t stream)
{
    const float* feats = (const float*)d_in[0];
    unsigned int* out = (unsigned int*)d_out;
    char* ws = (char*)d_ws;
    unsigned char* bfA = (unsigned char*)(ws);
    unsigned char* bfB = (unsigned char*)(ws + OFF_B);
    float* sq     = (float*)(ws + OFF_SQ);
    float* U      = (float*)(ws + OFF_U);
    float* V      = (float*)(ws + OFF_V);
    float* alignP = (float*)(ws + OFF_AL);
    unsigned int* done = (unsigned int*)(ws + OFF_DONE);

    prep_kernel<<<1024, 256, 0, stream>>>(feats, bfA, bfB, sq, U, V, alignP, done);
    band_kernel<<<NBLK, 256, 0, stream>>>(bfA, bfB, sq, U, V, alignP, done, out);
}

// Round 9
// 116.675 us; speedup vs baseline: 2.0191x; 2.0191x over previous
//
#include <hip/hip_runtime.h>

#define N_HALF 8192
#define D 128
#define NBLK 2112

typedef float f32x4 __attribute__((ext_vector_type(4)));

// ws layout (4327424 B):
// [0,       2097152)  bfA  -- fp8 e4m3 of (-2*x), fragment-major kk-paired:
//                       frag(T,p,ni) @ ((T*2+p)*4+ni)*1024; lane l byte [l*16+h*8+j]
//                       = row T*64+ni*16+(l&15), k = (2p+h)*32+(l>>4)*8+j
// [2097152, 4194304)  bfB  -- fp8 e4m3 of (x), same layout
// [4194304, 4259840)  sq      (16384 f32)  -- exact fp32 |row|^2
// [4259840, 4292608)  U       (8192 f32)   -- rowsum_aa + rowsum_ab
// [4292608, 4325376)  V       (8192 f32)   -- colsum_ab + rowsum_bb
// [4325376, 4327424)  alignP  (512 f32)    -- per-a-block align partials
#define OFF_B  2097152
#define OFF_SQ 4194304
#define OFF_U  4259840
#define OFF_V  4292608
#define OFF_AL 4325376

union Frag { uint4 u; long h[2]; };

__device__ __forceinline__ unsigned short f2bf(float f) {
    unsigned int u = __float_as_uint(f);
    u += 0x7fffu + ((u >> 16) & 1u);   // round-to-nearest-even
    return (unsigned short)(u >> 16);
}

__device__ __forceinline__ void async_cp16(const void* g, void* l) {
    __builtin_amdgcn_global_load_lds(
        (const __attribute__((address_space(1))) void*)g,
        (__attribute__((address_space(3))) void*)l, 16, 0, 0);
}

// ---- prep: 1024 blocks, one 16-row single-side slice each. Exact fp32 norms +
// diag-align; emits fp8 fragments: bfA = fp8(-2x), bfB = fp8(x) (kk-paired).
__global__ __launch_bounds__(256) void prep_kernel(
    const float* __restrict__ feats, unsigned char* __restrict__ bfA,
    unsigned char* __restrict__ bfB,
    float* __restrict__ sq, float* __restrict__ U, float* __restrict__ V,
    float* __restrict__ alignP)
{
    __shared__ float ld[16 * 132];
    __shared__ float alg[16];

    const int side = blockIdx.x >> 9;          // 0 = a, 1 = b
    const int idx = blockIdx.x & 511;
    const int g0 = idx * 16;                   // first row within the half
    const int R = side * N_HALF + g0;          // global feature-row base
    const int t = threadIdx.x;

    // stage 16 rows (8 KB) coalesced
#pragma unroll
    for (int it = 0; it < 2; ++it) {
        int i4 = it * 256 + t;                 // 0..511 float4 slots
        int row = i4 >> 5, c4 = i4 & 31;
        *(float4*)&ld[row * 132 + c4 * 4] =
            *(const float4*)(feats + (size_t)(R + row) * D + c4 * 4);
    }
    if (t < 16) { if (side == 0) U[g0 + t] = 0.f; else V[g0 + t] = 0.f; }
    __syncthreads();

    const int r = t >> 4;                      // row 0..15 (16 threads/row)
    const int c = t & 15;
    float sa = 0.f;
#pragma unroll
    for (int k = 0; k < 8; k += 4) {
        float4 v = *(const float4*)&ld[r * 132 + c * 8 + k];
        sa += v.x * v.x + v.y * v.y + v.z * v.z + v.w * v.w;
    }
    sa += __shfl_xor(sa, 1);
    sa += __shfl_xor(sa, 2);
    sa += __shfl_xor(sa, 4);
    sa += __shfl_xor(sa, 8);
    if (c == 0) sq[R + r] = sa;

    if (side == 0) {   // exact diag alignment: dot(a_r, b_r) + local b-norm
        float dt = 0.f, sb = 0.f;
        const float* brow = feats + (size_t)(N_HALF + g0 + r) * D + c * 8;
#pragma unroll
        for (int k = 0; k < 8; k += 4) {
            float4 bv = *(const float4*)(brow + k);
            float4 av = *(const float4*)&ld[r * 132 + c * 8 + k];
            dt += av.x * bv.x + av.y * bv.y + av.z * bv.z + av.w * bv.w;
            sb += bv.x * bv.x + bv.y * bv.y + bv.z * bv.z + bv.w * bv.w;
        }
        dt += __shfl_xor(dt, 1); sb += __shfl_xor(sb, 1);
        dt += __shfl_xor(dt, 2); sb += __shfl_xor(sb, 2);
        dt += __shfl_xor(dt, 4); sb += __shfl_xor(sb, 4);
        dt += __shfl_xor(dt, 8); sb += __shfl_xor(sb, 8);
        if (c == 0) {
            float d2 = fmaxf(sa + sb - 2.0f * dt, 0.0f);
            alg[r] = -__logf(d2 + 1.0f);
        }
    }

    // fp8 fragment emission: (T = side*128+idx>>2, ni = idx&3); uint t of each
    // 1KB frag: l = t>>2, half = (t>>1)&1, j0 = (t&1)*4.
    const int l = t >> 2, half = (t >> 1) & 1, j0 = (t & 1) * 4;
    const int rloc = l & 15, quad = l >> 4;
    const size_t Tb = ((size_t)(side * 128 + (idx >> 2))) * 8 + (idx & 3);
#pragma unroll
    for (int p = 0; p < 2; ++p) {
        const int k = p * 64 + half * 32 + quad * 8 + j0;
        float4 v = *(const float4*)&ld[rloc * 132 + k];
        int ub = __builtin_amdgcn_cvt_pk_fp8_f32(v.x, v.y, 0, false);
        ub = __builtin_amdgcn_cvt_pk_fp8_f32(v.z, v.w, ub, true);
        int ua = __builtin_amdgcn_cvt_pk_fp8_f32(-2.f * v.x, -2.f * v.y, 0, false);
        ua = __builtin_amdgcn_cvt_pk_fp8_f32(-2.f * v.z, -2.f * v.w, ua, true);
        ((unsigned int*)bfA)[(Tb + p * 4) * 256 + t] = (unsigned int)ua;
        ((unsigned int*)bfB)[(Tb + p * 4) * 256 + t] = (unsigned int)ub;
    }
    if (side == 0) {
        __syncthreads();
        if (t == 0) {
            float s = 0.f;
#pragma unroll
            for (int rr = 0; rr < 16; ++rr) s += alg[rr];
            alignP[idx] = s;
        }
    }
}

// ---- band kernel, R9: R3 structure (53us champion) with the barrier convoy
// amortized 2x (T3/T4, m233): TWO column-tiles per barrier. Tiles 2k,2k+1 are
// contiguous 16KB in bfB -> one stage2 = 4 DMA/wave; barriers/job 8 -> 4,
// each barrier window hides ~2x compute. vmcnt(8) = drain stage (4 oldest),
// keep the 8 csq prefetches in flight. LDS 2x16K + 8K colP = 40960 B
// (512B-granular) -> 4 blocks/CU = exactly the 160 KiB pool.
// R7 lesson kept: launch_bounds(256,4), natural VGPR. R3's colP-zero bank
// conflict fixed (lane*4 stride).
__global__ __launch_bounds__(256, 4) void band_kernel(
    const unsigned char* __restrict__ bfA, const unsigned char* __restrict__ bfB,
    const float* __restrict__ sq, float* __restrict__ U, float* __restrict__ V)
{
    __shared__ unsigned char lB[2][16384];  // 2 x 16 KB B dbuf (2 tiles each)
    __shared__ float colP[4][512];          // per-wave col partials (8 KB)

    int kind, band, js;
    {
        int id = blockIdx.x;
        if (id < 1024) { kind = 0; band = id & 63; js = (id >> 6) * 8; }
        else {
            int t = id - 1024;
            kind = 1;
            if (t >= 544) { t -= 544; kind = 2; }
            int g = 0;
            while (t >= 4 * (16 - g)) { t -= 4 * (16 - g); ++g; }   // <=15 iters
            band = 4 * g + (t & 3);
            js = 8 * (g + (t >> 2));
        }
    }
    const bool sym = (kind != 0);

    const int wave = threadIdx.x >> 6, lane = threadIdx.x & 63;
    const int l15 = lane & 15, quad = lane >> 4;

    const int T_Aw = (kind == 2 ? 128 : 0) + 2 * band + (wave >> 1);
    const int niA0 = (wave & 1) * 2;
    const int T_B0 = (kind == 1 ? 0 : 128);
    const int rowSqB = (kind == 2 ? N_HALF : 0);
    const int colSqB = (kind == 1 ? 0 : N_HALF);
    float* const rowDst = (kind == 2) ? V : U;
    float* const colDst = (kind == 1) ? U : V;
    const int wRow0 = band * 128 + wave * 32;

    // each wave zeroes ITS OWN colP region; lane*4 stride = 64 consecutive
    // float4 slots, conflict-free (fixes R3's 135K bank-conflict events)
    {
        float4 z = make_float4(0.f, 0.f, 0.f, 0.f);
        *(float4*)&colP[wave][lane * 4] = z;
        *(float4*)&colP[wave][256 + lane * 4] = z;
    }

    // A fragments (32 rows, pre-scaled -2 in fp8): af[mi][p], 2 kk per b128
    Frag af[2][2];
#pragma unroll
    for (int mi = 0; mi < 2; ++mi)
#pragma unroll
        for (int p = 0; p < 2; ++p)
            af[mi][p].u = *(const uint4*)(bfA +
                ((size_t)T_Aw * 8 + p * 4 + niA0 + mi) * 1024 + lane * 16);

    float2 rs2[4];
#pragma unroll
    for (int mi = 0; mi < 2; ++mi)
#pragma unroll
        for (int rh = 0; rh < 2; ++rh) {
            const float* p = sq + rowSqB + wRow0 + mi * 16 + quad * 4 + 2 * rh;
            rs2[mi * 2 + rh] = make_float2(p[0] + 1.0f, p[1] + 1.0f);
        }

    float2 rowAcc2[4];
#pragma unroll
    for (int x = 0; x < 4; ++x) rowAcc2[x] = make_float2(0.f, 0.f);

    // stage tile-pair {tt, tt+1} (16 KB contiguous): 4 x 1KB DMA per wave
    auto stage2 = [&](int tt, int s) {
        const unsigned char* src = bfB + (size_t)(T_B0 + tt) * 8192 + wave * 4096 + lane * 16;
        unsigned char* dst = &lB[s][wave * 4096];
#pragma unroll
        for (int i = 0; i < 4; ++i)
            async_cp16(src + i * 1024, dst + i * 1024);
    };

    stage2(js, 0);
    __builtin_amdgcn_sched_barrier(0);         // pin: stage before csq loads
    float csqN[8];                             // csq for next pair: [ti*4+ni]
#pragma unroll
    for (int i = 0; i < 8; ++i)
        csqN[i] = sq[colSqB + (js + (i >> 2)) * 64 + (i & 3) * 16 + l15];

    for (int k = 0; k < 4; ++k) {
        const int s = k & 1;
        const int t0 = js + 2 * k;
        // counted drain: allow the 8 newest vmem (this iter's csq prefetch);
        // drains the 4 stage DMAs for pair k (issued last iter).
        asm volatile("s_waitcnt vmcnt(8)" ::: "memory");
        __builtin_amdgcn_s_barrier();
        if (k + 1 < 4) stage2(t0 + 2, s ^ 1);
        __builtin_amdgcn_sched_barrier(0);     // pin: stage above csq/compute

        const int tn = (k + 1 < 4) ? t0 + 2 : t0;
        float csqC[8];
#pragma unroll
        for (int i = 0; i < 8; ++i) csqC[i] = csqN[i];
#pragma unroll
        for (int i = 0; i < 8; ++i)
            csqN[i] = sq[colSqB + (tn + (i >> 2)) * 64 + (i & 3) * 16 + l15];

        if (sym && (t0 * 64 + 128) <= wRow0) continue;   // both tiles below diag

#pragma unroll
        for (int ti = 0; ti < 2; ++ti) {
            const int t = t0 + ti;
            if (sym && (t * 64 + 64) <= wRow0) continue; // this tile below diag

            // acc init = |a|^2+|b|^2+1 (packed); MFMA adds -2*dot => acc = d2+1
            f32x4 acc[2][4];
#pragma unroll
            for (int mi = 0; mi < 2; ++mi)
#pragma unroll
                for (int ni = 0; ni < 4; ++ni) {
                    float cs = csqC[ti * 4 + ni];
                    acc[mi][ni][0] = rs2[mi * 2].x + cs;
                    acc[mi][ni][1] = rs2[mi * 2].y + cs;
                    acc[mi][ni][2] = rs2[mi * 2 + 1].x + cs;
                    acc[mi][ni][3] = rs2[mi * 2 + 1].y + cs;
                }

#pragma unroll
            for (int p = 0; p < 2; ++p) {
                Frag bfr[4];
#pragma unroll
                for (int ni = 0; ni < 4; ++ni)
                    bfr[ni].u = *(const uint4*)
                        &lB[s][ti * 8192 + (p * 4 + ni) * 1024 + lane * 16];
#pragma unroll
                for (int h = 0; h < 2; ++h)
#pragma unroll
                    for (int mi = 0; mi < 2; ++mi)
#pragma unroll
                        for (int ni = 0; ni < 4; ++ni)
                            acc[mi][ni] = __builtin_amdgcn_mfma_f32_16x16x32_fp8_fp8(
                                af[mi][p].h[h], bfr[ni].h[h], acc[mi][ni], 0, 0, 0);
            }

            const bool maskDiag = sym && (t * 64 < wRow0 + 32);
            float colv[4];
            if (!maskDiag) {
                // packed epilogue. No fmax clamp: off-diagonal d2 >= ~80 even
                // with fp8 quantization error, so acc = d2+1 >> 1 here.
                float2 cp[4];
#pragma unroll
                for (int ni = 0; ni < 4; ++ni) cp[ni] = make_float2(0.f, 0.f);
#pragma unroll
                for (int mi = 0; mi < 2; ++mi)
#pragma unroll
                    for (int ni = 0; ni < 4; ++ni) {
                        float2 slo = make_float2(__builtin_amdgcn_rcpf(acc[mi][ni][0]),
                                                 __builtin_amdgcn_rcpf(acc[mi][ni][1]));
                        float2 shi = make_float2(__builtin_amdgcn_rcpf(acc[mi][ni][2]),
                                                 __builtin_amdgcn_rcpf(acc[mi][ni][3]));
                        rowAcc2[mi * 2].x += slo.x;     rowAcc2[mi * 2].y += slo.y;
                        rowAcc2[mi * 2 + 1].x += shi.x; rowAcc2[mi * 2 + 1].y += shi.y;
                        cp[ni].x += slo.x + shi.x;
                        cp[ni].y += slo.y + shi.y;
                    }
#pragma unroll
                for (int ni = 0; ni < 4; ++ni) colv[ni] = cp[ni].x + cp[ni].y;
            } else {
                // scalar masked path (diagonal-overlap tiles only) — keeps clamp
                float colPart[4] = {0.f, 0.f, 0.f, 0.f};
#pragma unroll
                for (int mi = 0; mi < 2; ++mi)
#pragma unroll
                    for (int ni = 0; ni < 4; ++ni)
#pragma unroll
                        for (int r = 0; r < 4; ++r) {
                            float sim = __builtin_amdgcn_rcpf(fmaxf(acc[mi][ni][r], 1.0f));
                            if ((t * 64 + ni * 16 + l15) <= (wRow0 + mi * 16 + quad * 4 + r))
                                sim = 0.0f;   // strict upper only
                            if (r & 1) rowAcc2[mi * 2 + (r >> 1)].y += sim;
                            else       rowAcc2[mi * 2 + (r >> 1)].x += sim;
                            colPart[ni] += sim;
                        }
#pragma unroll
                for (int ni = 0; ni < 4; ++ni) colv[ni] = colPart[ni];
            }

            // col partials -> LDS (plain ds_write, wave-private slot per step)
#pragma unroll
            for (int ni = 0; ni < 4; ++ni) {
                float cv = colv[ni];
                cv += __shfl_xor(cv, 16);
                cv += __shfl_xor(cv, 32);
                if (quad == 0) colP[wave][(t - js) * 64 + ni * 16 + l15] = cv;
            }
        }
    }

    // end-of-job col flush: cross-wave reduce in LDS, <=512 atomics per block
    __syncthreads();
    {
        int c = threadIdx.x;
#pragma unroll
        for (int rep = 0; rep < 2; ++rep, c += 256) {
            float sv = colP[0][c] + colP[1][c] + colP[2][c] + colP[3][c];
            if (sv != 0.f) atomicAdd(&colDst[js * 64 + c], sv);
        }
    }

    // row flush: reduce over 16 l15 lanes, one atomic per row, once per job
#pragma unroll
    for (int x = 0; x < 8; ++x) {
        float v = (x & 1) ? rowAcc2[x >> 1].y : rowAcc2[x >> 1].x;
        v += __shfl_xor(v, 1);
        v += __shfl_xor(v, 2);
        v += __shfl_xor(v, 4);
        v += __shfl_xor(v, 8);
        if (l15 == 0)
            atomicAdd(&rowDst[wRow0 + (x >> 2) * 16 + quad * 4 + (x & 3)], v);
    }
}

// ---- tail: sum logs of U,V + align partials -> loss (single block)
__global__ __launch_bounds__(1024) void tail_kernel(
    const float* __restrict__ U, const float* __restrict__ V,
    const float* __restrict__ alignP, unsigned int* __restrict__ out)
{
    const int tid = threadIdx.x;
    float s = 0.f;
    const float4* U4 = (const float4*)U;
    const float4* V4 = (const float4*)V;
#pragma unroll
    for (int k = 0; k < 2; ++k) {
        float4 u = U4[tid * 2 + k];
        float4 v = V4[tid * 2 + k];
        s += __logf(u.x) + __logf(u.y) + __logf(u.z) + __logf(u.w);
        s += __logf(v.x) + __logf(v.y) + __logf(v.z) + __logf(v.w);
    }
    float a = 0.f;
    if (tid < 128) {
        float4 t4 = ((const float4*)alignP)[tid];
        a = t4.x + t4.y + t4.z + t4.w;
    }
    float m = a - 0.5f * s;
#pragma unroll
    for (int off = 32; off; off >>= 1) m += __shfl_xor(m, off);
    __shared__ float ps[16];
    if ((tid & 63) == 0) ps[tid >> 6] = m;
    __syncthreads();
    if (tid == 0) {
        float tot = 0.f;
#pragma unroll
        for (int w = 0; w < 16; ++w) tot += ps[w];
        float loss = -(tot / (float)N_HALF);
        unsigned int h = (unsigned int)f2bf(loss);
        out[0] = (h << 16) | h;   // fp32 reader: loss @ bf16 precision; bf16 reader: h
    }
}

extern "C" void kernel_launch(void* const* d_in, const int* in_sizes, int n_in,
                              void* d_out, int out_size, void* d_ws, size_t ws_size,
                              hipStream_t stream)
{
    const float* feats = (const float*)d_in[0];
    unsigned int* out = (unsigned int*)d_out;
    char* ws = (char*)d_ws;
    unsigned char* bfA = (unsigned char*)(ws);
    unsigned char* bfB = (unsigned char*)(ws + OFF_B);
    float* sq     = (float*)(ws + OFF_SQ);
    float* U      = (float*)(ws + OFF_U);
    float* V      = (float*)(ws + OFF_V);
    float* alignP = (float*)(ws + OFF_AL);

    prep_kernel<<<1024, 256, 0, stream>>>(feats, bfA, bfB, sq, U, V, alignP);
    band_kernel<<<NBLK, 256, 0, stream>>>(bfA, bfB, sq, U, V);
    tail_kernel<<<1, 1024, 0, stream>>>(U, V, alignP, out);
}

// Round 10
// 115.225 us; speedup vs baseline: 2.0445x; 1.0126x over previous
//
#include <hip/hip_runtime.h>

#define N_HALF 8192
#define D 128
#define NBLK 2112

typedef float f32x4 __attribute__((ext_vector_type(4)));

// ws layout (4327424 B):
// [0,       2097152)  bfA  -- fp8 e4m3 of (-2*x), fragment-major kk-paired:
//                       frag(T,p,ni) @ ((T*2+p)*4+ni)*1024; lane l byte [l*16+h*8+j]
//                       = row T*64+ni*16+(l&15), k = (2p+h)*32+(l>>4)*8+j
// [2097152, 4194304)  bfB  -- fp8 e4m3 of (x), same layout
// [4194304, 4259840)  sq      (16384 f32)  -- exact fp32 |row|^2
// [4259840, 4292608)  U       (8192 f32)   -- rowsum_aa + rowsum_ab
// [4292608, 4325376)  V       (8192 f32)   -- colsum_ab + rowsum_bb
// [4325376, 4327424)  alignP  (512 f32)    -- per-a-block align partials
#define OFF_B  2097152
#define OFF_SQ 4194304
#define OFF_U  4259840
#define OFF_V  4292608
#define OFF_AL 4325376

union Frag { uint4 u; long h[2]; };

__device__ __forceinline__ unsigned short f2bf(float f) {
    unsigned int u = __float_as_uint(f);
    u += 0x7fffu + ((u >> 16) & 1u);   // round-to-nearest-even
    return (unsigned short)(u >> 16);
}

__device__ __forceinline__ void async_cp16(const void* g, void* l) {
    __builtin_amdgcn_global_load_lds(
        (const __attribute__((address_space(1))) void*)g,
        (__attribute__((address_space(3))) void*)l, 16, 0, 0);
}

// ---- prep: 1024 blocks, one 16-row single-side slice each. Exact fp32 norms +
// diag-align; emits fp8 fragments: bfA = fp8(-2x), bfB = fp8(x) (kk-paired).
__global__ __launch_bounds__(256) void prep_kernel(
    const float* __restrict__ feats, unsigned char* __restrict__ bfA,
    unsigned char* __restrict__ bfB,
    float* __restrict__ sq, float* __restrict__ U, float* __restrict__ V,
    float* __restrict__ alignP)
{
    __shared__ float ld[16 * 132];
    __shared__ float alg[16];

    const int side = blockIdx.x >> 9;          // 0 = a, 1 = b
    const int idx = blockIdx.x & 511;
    const int g0 = idx * 16;                   // first row within the half
    const int R = side * N_HALF + g0;          // global feature-row base
    const int t = threadIdx.x;

    // stage 16 rows (8 KB) coalesced
#pragma unroll
    for (int it = 0; it < 2; ++it) {
        int i4 = it * 256 + t;                 // 0..511 float4 slots
        int row = i4 >> 5, c4 = i4 & 31;
        *(float4*)&ld[row * 132 + c4 * 4] =
            *(const float4*)(feats + (size_t)(R + row) * D + c4 * 4);
    }
    if (t < 16) { if (side == 0) U[g0 + t] = 0.f; else V[g0 + t] = 0.f; }
    __syncthreads();

    const int r = t >> 4;                      // row 0..15 (16 threads/row)
    const int c = t & 15;
    float sa = 0.f;
#pragma unroll
    for (int k = 0; k < 8; k += 4) {
        float4 v = *(const float4*)&ld[r * 132 + c * 8 + k];
        sa += v.x * v.x + v.y * v.y + v.z * v.z + v.w * v.w;
    }
    sa += __shfl_xor(sa, 1);
    sa += __shfl_xor(sa, 2);
    sa += __shfl_xor(sa, 4);
    sa += __shfl_xor(sa, 8);
    if (c == 0) sq[R + r] = sa;

    if (side == 0) {   // exact diag alignment: dot(a_r, b_r) + local b-norm
        float dt = 0.f, sb = 0.f;
        const float* brow = feats + (size_t)(N_HALF + g0 + r) * D + c * 8;
#pragma unroll
        for (int k = 0; k < 8; k += 4) {
            float4 bv = *(const float4*)(brow + k);
            float4 av = *(const float4*)&ld[r * 132 + c * 8 + k];
            dt += av.x * bv.x + av.y * bv.y + av.z * bv.z + av.w * bv.w;
            sb += bv.x * bv.x + bv.y * bv.y + bv.z * bv.z + bv.w * bv.w;
        }
        dt += __shfl_xor(dt, 1); sb += __shfl_xor(sb, 1);
        dt += __shfl_xor(dt, 2); sb += __shfl_xor(sb, 2);
        dt += __shfl_xor(dt, 4); sb += __shfl_xor(sb, 4);
        dt += __shfl_xor(dt, 8); sb += __shfl_xor(sb, 8);
        if (c == 0) {
            float d2 = fmaxf(sa + sb - 2.0f * dt, 0.0f);
            alg[r] = -__logf(d2 + 1.0f);
        }
    }

    // fp8 fragment emission: (T = side*128+idx>>2, ni = idx&3); uint t of each
    // 1KB frag: l = t>>2, half = (t>>1)&1, j0 = (t&1)*4.
    const int l = t >> 2, half = (t >> 1) & 1, j0 = (t & 1) * 4;
    const int rloc = l & 15, quad = l >> 4;
    const size_t Tb = ((size_t)(side * 128 + (idx >> 2))) * 8 + (idx & 3);
#pragma unroll
    for (int p = 0; p < 2; ++p) {
        const int k = p * 64 + half * 32 + quad * 8 + j0;
        float4 v = *(const float4*)&ld[rloc * 132 + k];
        int ub = __builtin_amdgcn_cvt_pk_fp8_f32(v.x, v.y, 0, false);
        ub = __builtin_amdgcn_cvt_pk_fp8_f32(v.z, v.w, ub, true);
        int ua = __builtin_amdgcn_cvt_pk_fp8_f32(-2.f * v.x, -2.f * v.y, 0, false);
        ua = __builtin_amdgcn_cvt_pk_fp8_f32(-2.f * v.z, -2.f * v.w, ua, true);
        ((unsigned int*)bfA)[(Tb + p * 4) * 256 + t] = (unsigned int)ua;
        ((unsigned int*)bfB)[(Tb + p * 4) * 256 + t] = (unsigned int)ub;
    }
    if (side == 0) {
        __syncthreads();
        if (t == 0) {
            float s = 0.f;
#pragma unroll
            for (int rr = 0; rr < 16; ++rr) s += alg[rr];
            alignP[idx] = s;
        }
    }
}

// ---- band kernel, R10: R9's barrier amortization (2 tiles per barrier,
// barriers/job 8->4) with the scratch hazard designed out:
//  - ALL 32 csq values pre-loaded into csqAll[32] BEFORE the loop (sq is
//    L1/L2-resident; one-time cost). No loop-carried arrays.
//  - pair-loop FULLY UNROLLED -> every index compile-time, SROA keeps
//    everything in registers (R9's csq rotation spilled: WRITE 8.4->47MB).
//  - only outstanding vmem at each barrier = previous stage2's 4 DMAs
//    (issued a full iteration earlier, long complete) -> vmcnt(0) is free.
// Rest identical to the R3 champion (LDS col partials, end-of-job flush,
// launch_bounds(256,4), conflict-free colP zeroing).
__global__ __launch_bounds__(256, 4) void band_kernel(
    const unsigned char* __restrict__ bfA, const unsigned char* __restrict__ bfB,
    const float* __restrict__ sq, float* __restrict__ U, float* __restrict__ V)
{
    __shared__ unsigned char lB[2][16384];  // 2 x 16 KB B dbuf (2 tiles each)
    __shared__ float colP[4][512];          // per-wave col partials (8 KB)

    int kind, band, js;
    {
        int id = blockIdx.x;
        if (id < 1024) { kind = 0; band = id & 63; js = (id >> 6) * 8; }
        else {
            int t = id - 1024;
            kind = 1;
            if (t >= 544) { t -= 544; kind = 2; }
            int g = 0;
            while (t >= 4 * (16 - g)) { t -= 4 * (16 - g); ++g; }   // <=15 iters
            band = 4 * g + (t & 3);
            js = 8 * (g + (t >> 2));
        }
    }
    const bool sym = (kind != 0);

    const int wave = threadIdx.x >> 6, lane = threadIdx.x & 63;
    const int l15 = lane & 15, quad = lane >> 4;

    const int T_Aw = (kind == 2 ? 128 : 0) + 2 * band + (wave >> 1);
    const int niA0 = (wave & 1) * 2;
    const int T_B0 = (kind == 1 ? 0 : 128);
    const int rowSqB = (kind == 2 ? N_HALF : 0);
    const int colSqB = (kind == 1 ? 0 : N_HALF);
    float* const rowDst = (kind == 2) ? V : U;
    float* const colDst = (kind == 1) ? U : V;
    const int wRow0 = band * 128 + wave * 32;

    // each wave zeroes ITS OWN colP region; lane*4 stride = 64 consecutive
    // float4 slots, conflict-free
    {
        float4 z = make_float4(0.f, 0.f, 0.f, 0.f);
        *(float4*)&colP[wave][lane * 4] = z;
        *(float4*)&colP[wave][256 + lane * 4] = z;
    }

    // A fragments (32 rows, pre-scaled -2 in fp8): af[mi][p], 2 kk per b128
    Frag af[2][2];
#pragma unroll
    for (int mi = 0; mi < 2; ++mi)
#pragma unroll
        for (int p = 0; p < 2; ++p)
            af[mi][p].u = *(const uint4*)(bfA +
                ((size_t)T_Aw * 8 + p * 4 + niA0 + mi) * 1024 + lane * 16);

    float2 rs2[4];
#pragma unroll
    for (int mi = 0; mi < 2; ++mi)
#pragma unroll
        for (int rh = 0; rh < 2; ++rh) {
            const float* p = sq + rowSqB + wRow0 + mi * 16 + quad * 4 + 2 * rh;
            rs2[mi * 2 + rh] = make_float2(p[0] + 1.0f, p[1] + 1.0f);
        }

    float2 rowAcc2[4];
#pragma unroll
    for (int x = 0; x < 4; ++x) rowAcc2[x] = make_float2(0.f, 0.f);

    // stage tile-pair {tt, tt+1} (16 KB contiguous): 4 x 1KB DMA per wave
    auto stage2 = [&](int tt, int s) {
        const unsigned char* src = bfB + (size_t)(T_B0 + tt) * 8192 + wave * 4096 + lane * 16;
        unsigned char* dst = &lB[s][wave * 4096];
#pragma unroll
        for (int i = 0; i < 4; ++i)
            async_cp16(src + i * 1024, dst + i * 1024);
    };

    stage2(js, 0);
    __builtin_amdgcn_sched_barrier(0);         // pin: stage before csq loads

    // all 8 tiles' col norms up-front: csqAll[(t-js)*4+ni], 32 one-time
    // L2-hit loads -> 32 registers (fully static indexing everywhere below)
    float csqAll[32];
#pragma unroll
    for (int i = 0; i < 32; ++i)
        csqAll[i] = sq[colSqB + js * 64 + i * 16 + l15];

#pragma unroll
    for (int k = 0; k < 4; ++k) {
        const int s = k & 1;
        const int t0 = js + 2 * k;
        // only the previous stage2's 4 DMAs are outstanding here (issued a
        // full iteration ago) -> this wait is ~free.
        asm volatile("s_waitcnt vmcnt(0)" ::: "memory");
        __builtin_amdgcn_s_barrier();
        if (k + 1 < 4) stage2(t0 + 2, s ^ 1);
        __builtin_amdgcn_sched_barrier(0);     // pin: stage above compute

        if (sym && (t0 * 64 + 128) <= wRow0) continue;   // both tiles below diag

#pragma unroll
        for (int ti = 0; ti < 2; ++ti) {
            const int t = t0 + ti;
            if (sym && (t * 64 + 64) <= wRow0) continue; // this tile below diag

            // acc init = |a|^2+|b|^2+1 (packed); MFMA adds -2*dot => acc = d2+1
            f32x4 acc[2][4];
#pragma unroll
            for (int mi = 0; mi < 2; ++mi)
#pragma unroll
                for (int ni = 0; ni < 4; ++ni) {
                    float cs = csqAll[(2 * k + ti) * 4 + ni];
                    acc[mi][ni][0] = rs2[mi * 2].x + cs;
                    acc[mi][ni][1] = rs2[mi * 2].y + cs;
                    acc[mi][ni][2] = rs2[mi * 2 + 1].x + cs;
                    acc[mi][ni][3] = rs2[mi * 2 + 1].y + cs;
                }

#pragma unroll
            for (int p = 0; p < 2; ++p) {
                Frag bfr[4];
#pragma unroll
                for (int ni = 0; ni < 4; ++ni)
                    bfr[ni].u = *(const uint4*)
                        &lB[s][ti * 8192 + (p * 4 + ni) * 1024 + lane * 16];
#pragma unroll
                for (int h = 0; h < 2; ++h)
#pragma unroll
                    for (int mi = 0; mi < 2; ++mi)
#pragma unroll
                        for (int ni = 0; ni < 4; ++ni)
                            acc[mi][ni] = __builtin_amdgcn_mfma_f32_16x16x32_fp8_fp8(
                                af[mi][p].h[h], bfr[ni].h[h], acc[mi][ni], 0, 0, 0);
            }

            const bool maskDiag = sym && (t * 64 < wRow0 + 32);
            float colv[4];
            if (!maskDiag) {
                // packed epilogue. No fmax clamp: off-diagonal d2 >= ~80 even
                // with fp8 quantization error, so acc = d2+1 >> 1 here.
                float2 cp[4];
#pragma unroll
                for (int ni = 0; ni < 4; ++ni) cp[ni] = make_float2(0.f, 0.f);
#pragma unroll
                for (int mi = 0; mi < 2; ++mi)
#pragma unroll
                    for (int ni = 0; ni < 4; ++ni) {
                        float2 slo = make_float2(__builtin_amdgcn_rcpf(acc[mi][ni][0]),
                                                 __builtin_amdgcn_rcpf(acc[mi][ni][1]));
                        float2 shi = make_float2(__builtin_amdgcn_rcpf(acc[mi][ni][2]),
                                                 __builtin_amdgcn_rcpf(acc[mi][ni][3]));
                        rowAcc2[mi * 2].x += slo.x;     rowAcc2[mi * 2].y += slo.y;
                        rowAcc2[mi * 2 + 1].x += shi.x; rowAcc2[mi * 2 + 1].y += shi.y;
                        cp[ni].x += slo.x + shi.x;
                        cp[ni].y += slo.y + shi.y;
                    }
#pragma unroll
                for (int ni = 0; ni < 4; ++ni) colv[ni] = cp[ni].x + cp[ni].y;
            } else {
                // scalar masked path (diagonal-overlap tiles only) — keeps clamp
                float colPart[4] = {0.f, 0.f, 0.f, 0.f};
#pragma unroll
                for (int mi = 0; mi < 2; ++mi)
#pragma unroll
                    for (int ni = 0; ni < 4; ++ni)
#pragma unroll
                        for (int r = 0; r < 4; ++r) {
                            float sim = __builtin_amdgcn_rcpf(fmaxf(acc[mi][ni][r], 1.0f));
                            if ((t * 64 + ni * 16 + l15) <= (wRow0 + mi * 16 + quad * 4 + r))
                                sim = 0.0f;   // strict upper only
                            if (r & 1) rowAcc2[mi * 2 + (r >> 1)].y += sim;
                            else       rowAcc2[mi * 2 + (r >> 1)].x += sim;
                            colPart[ni] += sim;
                        }
#pragma unroll
                for (int ni = 0; ni < 4; ++ni) colv[ni] = colPart[ni];
            }

            // col partials -> LDS (plain ds_write, wave-private slot per step)
#pragma unroll
            for (int ni = 0; ni < 4; ++ni) {
                float cv = colv[ni];
                cv += __shfl_xor(cv, 16);
                cv += __shfl_xor(cv, 32);
                if (quad == 0) colP[wave][(2 * k + ti) * 64 + ni * 16 + l15] = cv;
            }
        }
    }

    // end-of-job col flush: cross-wave reduce in LDS, <=512 atomics per block
    __syncthreads();
    {
        int c = threadIdx.x;
#pragma unroll
        for (int rep = 0; rep < 2; ++rep, c += 256) {
            float sv = colP[0][c] + colP[1][c] + colP[2][c] + colP[3][c];
            if (sv != 0.f) atomicAdd(&colDst[js * 64 + c], sv);
        }
    }

    // row flush: reduce over 16 l15 lanes, one atomic per row, once per job
#pragma unroll
    for (int x = 0; x < 8; ++x) {
        float v = (x & 1) ? rowAcc2[x >> 1].y : rowAcc2[x >> 1].x;
        v += __shfl_xor(v, 1);
        v += __shfl_xor(v, 2);
        v += __shfl_xor(v, 4);
        v += __shfl_xor(v, 8);
        if (l15 == 0)
            atomicAdd(&rowDst[wRow0 + (x >> 2) * 16 + quad * 4 + (x & 3)], v);
    }
}

// ---- tail: sum logs of U,V + align partials -> loss (single block)
__global__ __launch_bounds__(1024) void tail_kernel(
    const float* __restrict__ U, const float* __restrict__ V,
    const float* __restrict__ alignP, unsigned int* __restrict__ out)
{
    const int tid = threadIdx.x;
    float s = 0.f;
    const float4* U4 = (const float4*)U;
    const float4* V4 = (const float4*)V;
#pragma unroll
    for (int k = 0; k < 2; ++k) {
        float4 u = U4[tid * 2 + k];
        float4 v = V4[tid * 2 + k];
        s += __logf(u.x) + __logf(u.y) + __logf(u.z) + __logf(u.w);
        s += __logf(v.x) + __logf(v.y) + __logf(v.z) + __logf(v.w);
    }
    float a = 0.f;
    if (tid < 128) {
        float4 t4 = ((const float4*)alignP)[tid];
        a = t4.x + t4.y + t4.z + t4.w;
    }
    float m = a - 0.5f * s;
#pragma unroll
    for (int off = 32; off; off >>= 1) m += __shfl_xor(m, off);
    __shared__ float ps[16];
    if ((tid & 63) == 0) ps[tid >> 6] = m;
    __syncthreads();
    if (tid == 0) {
        float tot = 0.f;
#pragma unroll
        for (int w = 0; w < 16; ++w) tot += ps[w];
        float loss = -(tot / (float)N_HALF);
        unsigned int h = (unsigned int)f2bf(loss);
        out[0] = (h << 16) | h;   // fp32 reader: loss @ bf16 precision; bf16 reader: h
    }
}

extern "C" void kernel_launch(void* const* d_in, const int* in_sizes, int n_in,
                              void* d_out, int out_size, void* d_ws, size_t ws_size,
                              hipStream_t stream)
{
    const float* feats = (const float*)d_in[0];
    unsigned int* out = (unsigned int*)d_out;
    char* ws = (char*)d_ws;
    unsigned char* bfA = (unsigned char*)(ws);
    unsigned char* bfB = (unsigned char*)(ws + OFF_B);
    float* sq     = (float*)(ws + OFF_SQ);
    float* U      = (float*)(ws + OFF_U);
    float* V      = (float*)(ws + OFF_V);
    float* alignP = (float*)(ws + OFF_AL);

    prep_kernel<<<1024, 256, 0, stream>>>(feats, bfA, bfB, sq, U, V, alignP);
    band_kernel<<<NBLK, 256, 0, stream>>>(bfA, bfB, sq, U, V);
    tail_kernel<<<1, 1024, 0, stream>>>(U, V, alignP, out);
}

// Round 11
// 111.641 us; speedup vs baseline: 2.1101x; 1.0321x over previous
//
#include <hip/hip_runtime.h>

#define N_HALF 8192
#define D 128
#define NBLK 4224

typedef float f32x4 __attribute__((ext_vector_type(4)));

// ws layout (4327424 B):
// [0,       2097152)  bfA  -- fp8 e4m3 of (-2*x), fragment-major kk-paired:
//                       frag(T,p,ni) @ ((T*2+p)*4+ni)*1024; lane l byte [l*16+h*8+j]
//                       = row T*64+ni*16+(l&15), k = (2p+h)*32+(l>>4)*8+j
// [2097152, 4194304)  bfB  -- fp8 e4m3 of (x), same layout
// [4194304, 4259840)  sq      (16384 f32)  -- exact fp32 |row|^2
// [4259840, 4292608)  U       (8192 f32)   -- rowsum_aa + rowsum_ab
// [4292608, 4325376)  V       (8192 f32)   -- colsum_ab + rowsum_bb
// [4325376, 4327424)  alignP  (512 f32)    -- per-a-block align partials
#define OFF_B  2097152
#define OFF_SQ 4194304
#define OFF_U  4259840
#define OFF_V  4292608
#define OFF_AL 4325376

union Frag { uint4 u; long h[2]; };

__device__ __forceinline__ unsigned short f2bf(float f) {
    unsigned int u = __float_as_uint(f);
    u += 0x7fffu + ((u >> 16) & 1u);   // round-to-nearest-even
    return (unsigned short)(u >> 16);
}

__device__ __forceinline__ void async_cp16(const void* g, void* l) {
    __builtin_amdgcn_global_load_lds(
        (const __attribute__((address_space(1))) void*)g,
        (__attribute__((address_space(3))) void*)l, 16, 0, 0);
}

// ---- prep: 1024 blocks, one 16-row single-side slice each. Exact fp32 norms +
// diag-align; emits fp8 fragments: bfA = fp8(-2x), bfB = fp8(x) (kk-paired).
__global__ __launch_bounds__(256) void prep_kernel(
    const float* __restrict__ feats, unsigned char* __restrict__ bfA,
    unsigned char* __restrict__ bfB,
    float* __restrict__ sq, float* __restrict__ U, float* __restrict__ V,
    float* __restrict__ alignP)
{
    __shared__ float ld[16 * 132];
    __shared__ float alg[16];

    const int side = blockIdx.x >> 9;          // 0 = a, 1 = b
    const int idx = blockIdx.x & 511;
    const int g0 = idx * 16;                   // first row within the half
    const int R = side * N_HALF + g0;          // global feature-row base
    const int t = threadIdx.x;

    // stage 16 rows (8 KB) coalesced
#pragma unroll
    for (int it = 0; it < 2; ++it) {
        int i4 = it * 256 + t;                 // 0..511 float4 slots
        int row = i4 >> 5, c4 = i4 & 31;
        *(float4*)&ld[row * 132 + c4 * 4] =
            *(const float4*)(feats + (size_t)(R + row) * D + c4 * 4);
    }
    if (t < 16) { if (side == 0) U[g0 + t] = 0.f; else V[g0 + t] = 0.f; }
    __syncthreads();

    const int r = t >> 4;                      // row 0..15 (16 threads/row)
    const int c = t & 15;
    float sa = 0.f;
#pragma unroll
    for (int k = 0; k < 8; k += 4) {
        float4 v = *(const float4*)&ld[r * 132 + c * 8 + k];
        sa += v.x * v.x + v.y * v.y + v.z * v.z + v.w * v.w;
    }
    sa += __shfl_xor(sa, 1);
    sa += __shfl_xor(sa, 2);
    sa += __shfl_xor(sa, 4);
    sa += __shfl_xor(sa, 8);
    if (c == 0) sq[R + r] = sa;

    if (side == 0) {   // exact diag alignment: dot(a_r, b_r) + local b-norm
        float dt = 0.f, sb = 0.f;
        const float* brow = feats + (size_t)(N_HALF + g0 + r) * D + c * 8;
#pragma unroll
        for (int k = 0; k < 8; k += 4) {
            float4 bv = *(const float4*)(brow + k);
            float4 av = *(const float4*)&ld[r * 132 + c * 8 + k];
            dt += av.x * bv.x + av.y * bv.y + av.z * bv.z + av.w * bv.w;
            sb += bv.x * bv.x + bv.y * bv.y + bv.z * bv.z + bv.w * bv.w;
        }
        dt += __shfl_xor(dt, 1); sb += __shfl_xor(sb, 1);
        dt += __shfl_xor(dt, 2); sb += __shfl_xor(sb, 2);
        dt += __shfl_xor(dt, 4); sb += __shfl_xor(sb, 4);
        dt += __shfl_xor(dt, 8); sb += __shfl_xor(sb, 8);
        if (c == 0) {
            float d2 = fmaxf(sa + sb - 2.0f * dt, 0.0f);
            alg[r] = -__logf(d2 + 1.0f);
        }
    }

    // fp8 fragment emission: (T = side*128+idx>>2, ni = idx&3); uint t of each
    // 1KB frag: l = t>>2, half = (t>>1)&1, j0 = (t&1)*4.
    const int l = t >> 2, half = (t >> 1) & 1, j0 = (t & 1) * 4;
    const int rloc = l & 15, quad = l >> 4;
    const size_t Tb = ((size_t)(side * 128 + (idx >> 2))) * 8 + (idx & 3);
#pragma unroll
    for (int p = 0; p < 2; ++p) {
        const int k = p * 64 + half * 32 + quad * 8 + j0;
        float4 v = *(const float4*)&ld[rloc * 132 + k];
        int ub = __builtin_amdgcn_cvt_pk_fp8_f32(v.x, v.y, 0, false);
        ub = __builtin_amdgcn_cvt_pk_fp8_f32(v.z, v.w, ub, true);
        int ua = __builtin_amdgcn_cvt_pk_fp8_f32(-2.f * v.x, -2.f * v.y, 0, false);
        ua = __builtin_amdgcn_cvt_pk_fp8_f32(-2.f * v.z, -2.f * v.w, ua, true);
        ((unsigned int*)bfA)[(Tb + p * 4) * 256 + t] = (unsigned int)ua;
        ((unsigned int*)bfB)[(Tb + p * 4) * 256 + t] = (unsigned int)ub;
    }
    if (side == 0) {
        __syncthreads();
        if (t == 0) {
            float s = 0.f;
#pragma unroll
            for (int rr = 0; rr < 16; ++rr) s += alg[rr];
            alignP[idx] = s;
        }
    }
}

// ---- band kernel, R11: R3's exact per-wave schedule (unchanged registers,
// unchanged vmcnt(4)+barrier staging, unchanged epilogue) repackaged into
// 2-WAVE BLOCKS: 64-row bands, 128 threads, lB 16KB + colP 4KB = 20KB/block
// -> 8 blocks/CU by LDS (16 waves/CU vs R3's ~10), and each barrier is a
// 2-wave rendezvous instead of 4 (convoy fan-in halved; independent blocks
// fill each other's barrier windows). Same 8448 wave-jobs as R3. Cost:
// col-flush covers 64 rows instead of 128 -> ~2x col atomics (~+6MB writes).
// Jobs: 2048 kind0 (128 bands x 16 col-groups) + 1088 per sym kind.
__global__ __launch_bounds__(128, 4) void band_kernel(
    const unsigned char* __restrict__ bfA, const unsigned char* __restrict__ bfB,
    const float* __restrict__ sq, float* __restrict__ U, float* __restrict__ V)
{
    __shared__ unsigned char lB[2][8192];   // 2 x 8 KB B dbuf
    __shared__ float colP[2][512];          // per-wave col partials (4 KB)

    int kind, band, js;
    {
        int id = blockIdx.x;
        if (id < 2048) { kind = 0; band = id & 127; js = (id >> 7) * 8; }
        else {
            int t = id - 2048;
            kind = 1;
            if (t >= 1088) { t -= 1088; kind = 2; }
            int g = 0;
            while (t >= 8 * (16 - g)) { t -= 8 * (16 - g); ++g; }   // <=15 iters
            band = 8 * g + (t & 7);
            js = 8 * (g + (t >> 3));
        }
    }
    const int je = js + 8;
    const bool sym = (kind != 0);

    const int wave = threadIdx.x >> 6, lane = threadIdx.x & 63;
    const int l15 = lane & 15, quad = lane >> 4;

    const int T_Aw = (kind == 2 ? 128 : 0) + band;   // 64-row A-tile = band
    const int niA0 = wave * 2;                        // wave0: ni 0,1; wave1: 2,3
    const int T_B0 = (kind == 1 ? 0 : 128);
    const int rowSqB = (kind == 2 ? N_HALF : 0);
    const int colSqB = (kind == 1 ? 0 : N_HALF);
    float* const rowDst = (kind == 2) ? V : U;
    float* const colDst = (kind == 1) ? U : V;
    const int wRow0 = band * 64 + wave * 32;

    // each wave zeroes ITS OWN colP region; lane*4 stride (conflict-free)
    {
        float4 z = make_float4(0.f, 0.f, 0.f, 0.f);
        *(float4*)&colP[wave][lane * 4] = z;
        *(float4*)&colP[wave][256 + lane * 4] = z;
    }

    // A fragments (32 rows, pre-scaled -2 in fp8): af[mi][p], 2 kk per b128
    Frag af[2][2];
#pragma unroll
    for (int mi = 0; mi < 2; ++mi)
#pragma unroll
        for (int p = 0; p < 2; ++p)
            af[mi][p].u = *(const uint4*)(bfA +
                ((size_t)T_Aw * 8 + p * 4 + niA0 + mi) * 1024 + lane * 16);

    float2 rs2[4];
#pragma unroll
    for (int mi = 0; mi < 2; ++mi)
#pragma unroll
        for (int rh = 0; rh < 2; ++rh) {
            const float* p = sq + rowSqB + wRow0 + mi * 16 + quad * 4 + 2 * rh;
            rs2[mi * 2 + rh] = make_float2(p[0] + 1.0f, p[1] + 1.0f);
        }

    float2 rowAcc2[4];
#pragma unroll
    for (int x = 0; x < 4; ++x) rowAcc2[x] = make_float2(0.f, 0.f);

    // stage tile t (8 KB): each of 2 waves copies 4KB via 4 x 1KB DMA instrs
    auto stage = [&](int t, int s) {
        const unsigned char* src = bfB + (size_t)(T_B0 + t) * 8192 + wave * 4096 + lane * 16;
        unsigned char* dst = &lB[s][wave * 4096];
#pragma unroll
        for (int i = 0; i < 4; ++i)
            async_cp16(src + i * 1024, dst + i * 1024);
    };

    stage(js, 0);
    __builtin_amdgcn_sched_barrier(0);         // pin: stage before csq loads
    float csqN[4];
#pragma unroll
    for (int ni = 0; ni < 4; ++ni)
        csqN[ni] = sq[colSqB + js * 64 + ni * 16 + l15];

    for (int t = js; t < je; ++t) {
        const int s = (t - js) & 1;
        // counted drain: allow the 4 newest vmem (this wave's csq prefetch);
        // drains this wave's 4 stage(t) DMAs. Barrier orders the other wave.
        asm volatile("s_waitcnt vmcnt(4)" ::: "memory");
        __builtin_amdgcn_s_barrier();
        if (t + 1 < je) stage(t + 1, s ^ 1);
        __builtin_amdgcn_sched_barrier(0);     // pin: stage above csq/compute

        const int jn = (t + 1 < je) ? t + 1 : t;
        float csq[4] = {csqN[0], csqN[1], csqN[2], csqN[3]};
#pragma unroll
        for (int ni = 0; ni < 4; ++ni)
            csqN[ni] = sq[colSqB + jn * 64 + ni * 16 + l15];

        if (sym && (t * 64 + 64) <= wRow0) continue;   // fully below diagonal

        // acc init = |a|^2 + |b|^2 + 1 (packed); MFMA adds -2*dot => acc = d2+1
        f32x4 acc[2][4];
#pragma unroll
        for (int mi = 0; mi < 2; ++mi)
#pragma unroll
            for (int ni = 0; ni < 4; ++ni) {
                acc[mi][ni][0] = rs2[mi * 2].x + csq[ni];
                acc[mi][ni][1] = rs2[mi * 2].y + csq[ni];
                acc[mi][ni][2] = rs2[mi * 2 + 1].x + csq[ni];
                acc[mi][ni][3] = rs2[mi * 2 + 1].y + csq[ni];
            }

#pragma unroll
        for (int p = 0; p < 2; ++p) {
            Frag bfr[4];
#pragma unroll
            for (int ni = 0; ni < 4; ++ni)
                bfr[ni].u = *(const uint4*)&lB[s][(p * 4 + ni) * 1024 + lane * 16];
#pragma unroll
            for (int h = 0; h < 2; ++h)
#pragma unroll
                for (int mi = 0; mi < 2; ++mi)
#pragma unroll
                    for (int ni = 0; ni < 4; ++ni)
                        acc[mi][ni] = __builtin_amdgcn_mfma_f32_16x16x32_fp8_fp8(
                            af[mi][p].h[h], bfr[ni].h[h], acc[mi][ni], 0, 0, 0);
        }

        const bool maskDiag = sym && (t * 64 < wRow0 + 32);
        float colv[4];
        if (!maskDiag) {
            // packed epilogue. No fmax clamp: off-diagonal d2 >= ~80 even with
            // fp8 quantization error, so acc = d2+1 is always >> 1 here.
            float2 cp[4];
#pragma unroll
            for (int ni = 0; ni < 4; ++ni) cp[ni] = make_float2(0.f, 0.f);
#pragma unroll
            for (int mi = 0; mi < 2; ++mi)
#pragma unroll
                for (int ni = 0; ni < 4; ++ni) {
                    float2 slo = make_float2(__builtin_amdgcn_rcpf(acc[mi][ni][0]),
                                             __builtin_amdgcn_rcpf(acc[mi][ni][1]));
                    float2 shi = make_float2(__builtin_amdgcn_rcpf(acc[mi][ni][2]),
                                             __builtin_amdgcn_rcpf(acc[mi][ni][3]));
                    rowAcc2[mi * 2].x += slo.x;     rowAcc2[mi * 2].y += slo.y;
                    rowAcc2[mi * 2 + 1].x += shi.x; rowAcc2[mi * 2 + 1].y += shi.y;
                    cp[ni].x += slo.x + shi.x;
                    cp[ni].y += slo.y + shi.y;
                }
#pragma unroll
            for (int ni = 0; ni < 4; ++ni) colv[ni] = cp[ni].x + cp[ni].y;
        } else {
            // scalar masked path (diagonal-overlap tiles only) — keeps clamp
            float colPart[4] = {0.f, 0.f, 0.f, 0.f};
#pragma unroll
            for (int mi = 0; mi < 2; ++mi)
#pragma unroll
                for (int ni = 0; ni < 4; ++ni)
#pragma unroll
                    for (int r = 0; r < 4; ++r) {
                        float sim = __builtin_amdgcn_rcpf(fmaxf(acc[mi][ni][r], 1.0f));
                        if ((t * 64 + ni * 16 + l15) <= (wRow0 + mi * 16 + quad * 4 + r))
                            sim = 0.0f;   // strict upper only
                        if (r & 1) rowAcc2[mi * 2 + (r >> 1)].y += sim;
                        else       rowAcc2[mi * 2 + (r >> 1)].x += sim;
                        colPart[ni] += sim;
                    }
#pragma unroll
            for (int ni = 0; ni < 4; ++ni) colv[ni] = colPart[ni];
        }

        // col partials -> LDS (plain ds_write, one slot per (wave,step,ni,l15))
#pragma unroll
        for (int ni = 0; ni < 4; ++ni) {
            float cv = colv[ni];
            cv += __shfl_xor(cv, 16);
            cv += __shfl_xor(cv, 32);
            if (quad == 0) colP[wave][(t - js) * 64 + ni * 16 + l15] = cv;
        }
    }

    // end-of-job col flush: cross-wave reduce in LDS, <=512 atomics per block
    __syncthreads();
    {
        int c = threadIdx.x;
#pragma unroll
        for (int rep = 0; rep < 4; ++rep, c += 128) {
            float sv = colP[0][c] + colP[1][c];
            if (sv != 0.f) atomicAdd(&colDst[js * 64 + c], sv);
        }
    }

    // row flush: reduce over 16 l15 lanes, one atomic per row, once per job
#pragma unroll
    for (int x = 0; x < 8; ++x) {
        float v = (x & 1) ? rowAcc2[x >> 1].y : rowAcc2[x >> 1].x;
        v += __shfl_xor(v, 1);
        v += __shfl_xor(v, 2);
        v += __shfl_xor(v, 4);
        v += __shfl_xor(v, 8);
        if (l15 == 0)
            atomicAdd(&rowDst[wRow0 + (x >> 2) * 16 + quad * 4 + (x & 3)], v);
    }
}

// ---- tail: sum logs of U,V + align partials -> loss (single block)
__global__ __launch_bounds__(1024) void tail_kernel(
    const float* __restrict__ U, const float* __restrict__ V,
    const float* __restrict__ alignP, unsigned int* __restrict__ out)
{
    const int tid = threadIdx.x;
    float s = 0.f;
    const float4* U4 = (const float4*)U;
    const float4* V4 = (const float4*)V;
#pragma unroll
    for (int k = 0; k < 2; ++k) {
        float4 u = U4[tid * 2 + k];
        float4 v = V4[tid * 2 + k];
        s += __logf(u.x) + __logf(u.y) + __logf(u.z) + __logf(u.w);
        s += __logf(v.x) + __logf(v.y) + __logf(v.z) + __logf(v.w);
    }
    float a = 0.f;
    if (tid < 128) {
        float4 t4 = ((const float4*)alignP)[tid];
        a = t4.x + t4.y + t4.z + t4.w;
    }
    float m = a - 0.5f * s;
#pragma unroll
    for (int off = 32; off; off >>= 1) m += __shfl_xor(m, off);
    __shared__ float ps[16];
    if ((tid & 63) == 0) ps[tid >> 6] = m;
    __syncthreads();
    if (tid == 0) {
        float tot = 0.f;
#pragma unroll
        for (int w = 0; w < 16; ++w) tot += ps[w];
        float loss = -(tot / (float)N_HALF);
        unsigned int h = (unsigned int)f2bf(loss);
        out[0] = (h << 16) | h;   // fp32 reader: loss @ bf16 precision; bf16 reader: h
    }
}

extern "C" void kernel_launch(void* const* d_in, const int* in_sizes, int n_in,
                              void* d_out, int out_size, void* d_ws, size_t ws_size,
                              hipStream_t stream)
{
    const float* feats = (const float*)d_in[0];
    unsigned int* out = (unsigned int*)d_out;
    char* ws = (char*)d_ws;
    unsigned char* bfA = (unsigned char*)(ws);
    unsigned char* bfB = (unsigned char*)(ws + OFF_B);
    float* sq     = (float*)(ws + OFF_SQ);
    float* U      = (float*)(ws + OFF_U);
    float* V      = (float*)(ws + OFF_V);
    float* alignP = (float*)(ws + OFF_AL);

    prep_kernel<<<1024, 256, 0, stream>>>(feats, bfA, bfB, sq, U, V, alignP);
    band_kernel<<<NBLK, 128, 0, stream>>>(bfA, bfB, sq, U, V);
    tail_kernel<<<1, 1024, 0, stream>>>(U, V, alignP, out);
}

// Round 12
// 109.391 us; speedup vs baseline: 2.1535x; 1.0206x over previous
//
#include <hip/hip_runtime.h>

#define N_HALF 8192
#define D 128
#define NBLK 2112

typedef float f32x4 __attribute__((ext_vector_type(4)));

// ws layout (4327424 B):
// [0,       2097152)  bfA  -- fp8 e4m3 of (-2*x), fragment-major kk-paired:
//                       frag(T,p,ni) @ ((T*2+p)*4+ni)*1024; lane l byte [l*16+h*8+j]
//                       = row T*64+ni*16+(l&15), k = (2p+h)*32+(l>>4)*8+j
// [2097152, 4194304)  bfB  -- fp8 e4m3 of (x), same layout
// [4194304, 4259840)  sq      (16384 f32)  -- exact fp32 |row|^2
// [4259840, 4292608)  U       (8192 f32)   -- rowsum_aa + rowsum_ab
// [4292608, 4325376)  V       (8192 f32)   -- colsum_ab + rowsum_bb
// [4325376, 4327424)  alignP  (512 f32)    -- per-a-block align partials
#define OFF_B  2097152
#define OFF_SQ 4194304
#define OFF_U  4259840
#define OFF_V  4292608
#define OFF_AL 4325376

union Frag { uint4 u; long h[2]; };

__device__ __forceinline__ unsigned short f2bf(float f) {
    unsigned int u = __float_as_uint(f);
    u += 0x7fffu + ((u >> 16) & 1u);   // round-to-nearest-even
    return (unsigned short)(u >> 16);
}

__device__ __forceinline__ void async_cp16(const void* g, void* l) {
    __builtin_amdgcn_global_load_lds(
        (const __attribute__((address_space(1))) void*)g,
        (__attribute__((address_space(3))) void*)l, 16, 0, 0);
}

// ---- prep: 1024 blocks, one 16-row single-side slice each. Exact fp32 norms +
// diag-align; emits fp8 fragments: bfA = fp8(-2x), bfB = fp8(x) (kk-paired).
__global__ __launch_bounds__(256) void prep_kernel(
    const float* __restrict__ feats, unsigned char* __restrict__ bfA,
    unsigned char* __restrict__ bfB,
    float* __restrict__ sq, float* __restrict__ U, float* __restrict__ V,
    float* __restrict__ alignP)
{
    __shared__ float ld[16 * 132];
    __shared__ float alg[16];

    const int side = blockIdx.x >> 9;          // 0 = a, 1 = b
    const int idx = blockIdx.x & 511;
    const int g0 = idx * 16;                   // first row within the half
    const int R = side * N_HALF + g0;          // global feature-row base
    const int t = threadIdx.x;

    // stage 16 rows (8 KB) coalesced
#pragma unroll
    for (int it = 0; it < 2; ++it) {
        int i4 = it * 256 + t;                 // 0..511 float4 slots
        int row = i4 >> 5, c4 = i4 & 31;
        *(float4*)&ld[row * 132 + c4 * 4] =
            *(const float4*)(feats + (size_t)(R + row) * D + c4 * 4);
    }
    if (t < 16) { if (side == 0) U[g0 + t] = 0.f; else V[g0 + t] = 0.f; }
    __syncthreads();

    const int r = t >> 4;                      // row 0..15 (16 threads/row)
    const int c = t & 15;
    float sa = 0.f;
#pragma unroll
    for (int k = 0; k < 8; k += 4) {
        float4 v = *(const float4*)&ld[r * 132 + c * 8 + k];
        sa += v.x * v.x + v.y * v.y + v.z * v.z + v.w * v.w;
    }
    sa += __shfl_xor(sa, 1);
    sa += __shfl_xor(sa, 2);
    sa += __shfl_xor(sa, 4);
    sa += __shfl_xor(sa, 8);
    if (c == 0) sq[R + r] = sa;

    if (side == 0) {   // exact diag alignment: dot(a_r, b_r) + local b-norm
        float dt = 0.f, sb = 0.f;
        const float* brow = feats + (size_t)(N_HALF + g0 + r) * D + c * 8;
#pragma unroll
        for (int k = 0; k < 8; k += 4) {
            float4 bv = *(const float4*)(brow + k);
            float4 av = *(const float4*)&ld[r * 132 + c * 8 + k];
            dt += av.x * bv.x + av.y * bv.y + av.z * bv.z + av.w * bv.w;
            sb += bv.x * bv.x + bv.y * bv.y + bv.z * bv.z + bv.w * bv.w;
        }
        dt += __shfl_xor(dt, 1); sb += __shfl_xor(sb, 1);
        dt += __shfl_xor(dt, 2); sb += __shfl_xor(sb, 2);
        dt += __shfl_xor(dt, 4); sb += __shfl_xor(sb, 4);
        dt += __shfl_xor(dt, 8); sb += __shfl_xor(sb, 8);
        if (c == 0) {
            float d2 = fmaxf(sa + sb - 2.0f * dt, 0.0f);
            alg[r] = -__logf(d2 + 1.0f);
        }
    }

    // fp8 fragment emission: (T = side*128+idx>>2, ni = idx&3); uint t of each
    // 1KB frag: l = t>>2, half = (t>>1)&1, j0 = (t&1)*4.
    const int l = t >> 2, half = (t >> 1) & 1, j0 = (t & 1) * 4;
    const int rloc = l & 15, quad = l >> 4;
    const size_t Tb = ((size_t)(side * 128 + (idx >> 2))) * 8 + (idx & 3);
#pragma unroll
    for (int p = 0; p < 2; ++p) {
        const int k = p * 64 + half * 32 + quad * 8 + j0;
        float4 v = *(const float4*)&ld[rloc * 132 + k];
        int ub = __builtin_amdgcn_cvt_pk_fp8_f32(v.x, v.y, 0, false);
        ub = __builtin_amdgcn_cvt_pk_fp8_f32(v.z, v.w, ub, true);
        int ua = __builtin_amdgcn_cvt_pk_fp8_f32(-2.f * v.x, -2.f * v.y, 0, false);
        ua = __builtin_amdgcn_cvt_pk_fp8_f32(-2.f * v.z, -2.f * v.w, ua, true);
        ((unsigned int*)bfA)[(Tb + p * 4) * 256 + t] = (unsigned int)ua;
        ((unsigned int*)bfB)[(Tb + p * 4) * 256 + t] = (unsigned int)ub;
    }
    if (side == 0) {
        __syncthreads();
        if (t == 0) {
            float s = 0.f;
#pragma unroll
            for (int rr = 0; rr < 16; ++rr) s += alg[rr];
            alignP[idx] = s;
        }
    }
}

// ---- band kernel, R12: R3 champion with PREFETCH DEPTH 2 (triple-buffered
// LDS DMA). R3's dbuf gives each 8KB stage exactly one compute window to
// complete; the immovable ~35% no-pipe stall (survived 7 structural probes)
// fits "DMA completion > one window". stage(t+2) each step gives every DMA
// two windows. No new register state (DMA is VGPR-free -- the R4/R9/R10
// spill trap is structurally avoided). LDS 3x8KB + 8KB colP = 32KB -> still
// 4 blocks/CU. vmcnt(6): at iter-t wait, ops newer than stage(t) are
// stage(t+1)[2] + csqN(t)[4]; compiler's csq-use waits never drain newer
// stages. Everything else byte-identical to R3.
__global__ __launch_bounds__(256, 4) void band_kernel(
    const unsigned char* __restrict__ bfA, const unsigned char* __restrict__ bfB,
    const float* __restrict__ sq, float* __restrict__ U, float* __restrict__ V)
{
    __shared__ unsigned char lB[3][8192];   // 3 x 8 KB B buffers
    __shared__ float colP[4][512];          // per-wave col partials (8 KB)

    int kind, band, js;
    {
        int id = blockIdx.x;
        if (id < 1024) { kind = 0; band = id & 63; js = (id >> 6) * 8; }
        else {
            int t = id - 1024;
            kind = 1;
            if (t >= 544) { t -= 544; kind = 2; }
            int g = 0;
            while (t >= 4 * (16 - g)) { t -= 4 * (16 - g); ++g; }   // <=15 iters
            band = 4 * g + (t & 3);
            js = 8 * (g + (t >> 2));
        }
    }
    const int je = js + 8;
    const bool sym = (kind != 0);

    const int wave = threadIdx.x >> 6, lane = threadIdx.x & 63;
    const int l15 = lane & 15, quad = lane >> 4;

    const int T_Aw = (kind == 2 ? 128 : 0) + 2 * band + (wave >> 1);
    const int niA0 = (wave & 1) * 2;
    const int T_B0 = (kind == 1 ? 0 : 128);
    const int rowSqB = (kind == 2 ? N_HALF : 0);
    const int colSqB = (kind == 1 ? 0 : N_HALF);
    float* const rowDst = (kind == 2) ? V : U;
    float* const colDst = (kind == 1) ? U : V;
    const int wRow0 = band * 128 + wave * 32;

    // each wave zeroes ITS OWN colP region; lane*4 stride (conflict-free)
    {
        float4 z = make_float4(0.f, 0.f, 0.f, 0.f);
        *(float4*)&colP[wave][lane * 4] = z;
        *(float4*)&colP[wave][256 + lane * 4] = z;
    }

    // A fragments (32 rows, pre-scaled -2 in fp8): af[mi][p], 2 kk per b128
    Frag af[2][2];
#pragma unroll
    for (int mi = 0; mi < 2; ++mi)
#pragma unroll
        for (int p = 0; p < 2; ++p)
            af[mi][p].u = *(const uint4*)(bfA +
                ((size_t)T_Aw * 8 + p * 4 + niA0 + mi) * 1024 + lane * 16);

    float2 rs2[4];
#pragma unroll
    for (int mi = 0; mi < 2; ++mi)
#pragma unroll
        for (int rh = 0; rh < 2; ++rh) {
            const float* p = sq + rowSqB + wRow0 + mi * 16 + quad * 4 + 2 * rh;
            rs2[mi * 2 + rh] = make_float2(p[0] + 1.0f, p[1] + 1.0f);
        }

    float2 rowAcc2[4];
#pragma unroll
    for (int x = 0; x < 4; ++x) rowAcc2[x] = make_float2(0.f, 0.f);

    // stage tile t (8 KB contiguous): wave copies 2KB via 2 x 1KB DMA instrs
    auto stage = [&](int t, int s) {
        const unsigned char* src = bfB + (size_t)(T_B0 + t) * 8192 + wave * 2048 + lane * 16;
        unsigned char* dst = &lB[s][wave * 2048];
        async_cp16(src, dst);
        async_cp16(src + 1024, dst + 1024);
    };

    stage(js, 0);
    stage(js + 1, 1);                          // prefetch depth 2
    __builtin_amdgcn_sched_barrier(0);         // pin: stages before csq loads
    float csqN[4];
#pragma unroll
    for (int ni = 0; ni < 4; ++ni)
        csqN[ni] = sq[colSqB + js * 64 + ni * 16 + l15];

    for (int t = js; t < je; ++t) {
        const int d = t - js;                  // 0..7
        const int s = d - (d >= 6 ? 6 : (d >= 3 ? 3 : 0));   // d % 3, cheap
        // counted drain: allow 6 newest vmem (stage(t+1)[2] + csqN(t)[4]);
        // everything older -- including stage(t) -- must have landed.
        asm volatile("s_waitcnt vmcnt(6)" ::: "memory");
        __builtin_amdgcn_s_barrier();
        if (t + 2 < je) {
            const int d2 = d + 2;
            stage(t + 2, d2 - (d2 >= 6 ? 6 : (d2 >= 3 ? 3 : 0)));
        }
        __builtin_amdgcn_sched_barrier(0);     // pin: stage above csq/compute

        const int jn = (t + 1 < je) ? t + 1 : t;
        float csq[4] = {csqN[0], csqN[1], csqN[2], csqN[3]};
#pragma unroll
        for (int ni = 0; ni < 4; ++ni)
            csqN[ni] = sq[colSqB + jn * 64 + ni * 16 + l15];

        if (sym && (t * 64 + 64) <= wRow0) continue;   // fully below diagonal

        // acc init = |a|^2 + |b|^2 + 1 (packed); MFMA adds -2*dot => acc = d2+1
        f32x4 acc[2][4];
#pragma unroll
        for (int mi = 0; mi < 2; ++mi)
#pragma unroll
            for (int ni = 0; ni < 4; ++ni) {
                acc[mi][ni][0] = rs2[mi * 2].x + csq[ni];
                acc[mi][ni][1] = rs2[mi * 2].y + csq[ni];
                acc[mi][ni][2] = rs2[mi * 2 + 1].x + csq[ni];
                acc[mi][ni][3] = rs2[mi * 2 + 1].y + csq[ni];
            }

#pragma unroll
        for (int p = 0; p < 2; ++p) {
            Frag bfr[4];
#pragma unroll
            for (int ni = 0; ni < 4; ++ni)
                bfr[ni].u = *(const uint4*)&lB[s][(p * 4 + ni) * 1024 + lane * 16];
#pragma unroll
            for (int h = 0; h < 2; ++h)
#pragma unroll
                for (int mi = 0; mi < 2; ++mi)
#pragma unroll
                    for (int ni = 0; ni < 4; ++ni)
                        acc[mi][ni] = __builtin_amdgcn_mfma_f32_16x16x32_fp8_fp8(
                            af[mi][p].h[h], bfr[ni].h[h], acc[mi][ni], 0, 0, 0);
        }

        const bool maskDiag = sym && (t * 64 < wRow0 + 32);
        float colv[4];
        if (!maskDiag) {
            // packed epilogue. No fmax clamp: off-diagonal d2 >= ~80 even with
            // fp8 quantization error, so acc = d2+1 is always >> 1 here.
            float2 cp[4];
#pragma unroll
            for (int ni = 0; ni < 4; ++ni) cp[ni] = make_float2(0.f, 0.f);
#pragma unroll
            for (int mi = 0; mi < 2; ++mi)
#pragma unroll
                for (int ni = 0; ni < 4; ++ni) {
                    float2 slo = make_float2(__builtin_amdgcn_rcpf(acc[mi][ni][0]),
                                             __builtin_amdgcn_rcpf(acc[mi][ni][1]));
                    float2 shi = make_float2(__builtin_amdgcn_rcpf(acc[mi][ni][2]),
                                             __builtin_amdgcn_rcpf(acc[mi][ni][3]));
                    rowAcc2[mi * 2].x += slo.x;     rowAcc2[mi * 2].y += slo.y;
                    rowAcc2[mi * 2 + 1].x += shi.x; rowAcc2[mi * 2 + 1].y += shi.y;
                    cp[ni].x += slo.x + shi.x;
                    cp[ni].y += slo.y + shi.y;
                }
#pragma unroll
            for (int ni = 0; ni < 4; ++ni) colv[ni] = cp[ni].x + cp[ni].y;
        } else {
            // scalar masked path (diagonal-overlap tiles only) — keeps clamp
            float colPart[4] = {0.f, 0.f, 0.f, 0.f};
#pragma unroll
            for (int mi = 0; mi < 2; ++mi)
#pragma unroll
                for (int ni = 0; ni < 4; ++ni)
#pragma unroll
                    for (int r = 0; r < 4; ++r) {
                        float sim = __builtin_amdgcn_rcpf(fmaxf(acc[mi][ni][r], 1.0f));
                        if ((t * 64 + ni * 16 + l15) <= (wRow0 + mi * 16 + quad * 4 + r))
                            sim = 0.0f;   // strict upper only
                        if (r & 1) rowAcc2[mi * 2 + (r >> 1)].y += sim;
                        else       rowAcc2[mi * 2 + (r >> 1)].x += sim;
                        colPart[ni] += sim;
                    }
#pragma unroll
            for (int ni = 0; ni < 4; ++ni) colv[ni] = colPart[ni];
        }

        // col partials -> LDS (plain ds_write, one slot per (wave,step,ni,l15))
#pragma unroll
        for (int ni = 0; ni < 4; ++ni) {
            float cv = colv[ni];
            cv += __shfl_xor(cv, 16);
            cv += __shfl_xor(cv, 32);
            if (quad == 0) colP[wave][d * 64 + ni * 16 + l15] = cv;
        }
    }

    // end-of-job col flush: cross-wave reduce in LDS, <=512 atomics per block
    __syncthreads();
    {
        int c = threadIdx.x;
#pragma unroll
        for (int rep = 0; rep < 2; ++rep, c += 256) {
            float sv = colP[0][c] + colP[1][c] + colP[2][c] + colP[3][c];
            if (sv != 0.f) atomicAdd(&colDst[js * 64 + c], sv);
        }
    }

    // row flush: reduce over 16 l15 lanes, one atomic per row, once per job
#pragma unroll
    for (int x = 0; x < 8; ++x) {
        float v = (x & 1) ? rowAcc2[x >> 1].y : rowAcc2[x >> 1].x;
        v += __shfl_xor(v, 1);
        v += __shfl_xor(v, 2);
        v += __shfl_xor(v, 4);
        v += __shfl_xor(v, 8);
        if (l15 == 0)
            atomicAdd(&rowDst[wRow0 + (x >> 2) * 16 + quad * 4 + (x & 3)], v);
    }
}

// ---- tail: sum logs of U,V + align partials -> loss (single block)
__global__ __launch_bounds__(1024) void tail_kernel(
    const float* __restrict__ U, const float* __restrict__ V,
    const float* __restrict__ alignP, unsigned int* __restrict__ out)
{
    const int tid = threadIdx.x;
    float s = 0.f;
    const float4* U4 = (const float4*)U;
    const float4* V4 = (const float4*)V;
#pragma unroll
    for (int k = 0; k < 2; ++k) {
        float4 u = U4[tid * 2 + k];
        float4 v = V4[tid * 2 + k];
        s += __logf(u.x) + __logf(u.y) + __logf(u.z) + __logf(u.w);
        s += __logf(v.x) + __logf(v.y) + __logf(v.z) + __logf(v.w);
    }
    float a = 0.f;
    if (tid < 128) {
        float4 t4 = ((const float4*)alignP)[tid];
        a = t4.x + t4.y + t4.z + t4.w;
    }
    float m = a - 0.5f * s;
#pragma unroll
    for (int off = 32; off; off >>= 1) m += __shfl_xor(m, off);
    __shared__ float ps[16];
    if ((tid & 63) == 0) ps[tid >> 6] = m;
    __syncthreads();
    if (tid == 0) {
        float tot = 0.f;
#pragma unroll
        for (int w = 0; w < 16; ++w) tot += ps[w];
        float loss = -(tot / (float)N_HALF);
        unsigned int h = (unsigned int)f2bf(loss);
        out[0] = (h << 16) | h;   // fp32 reader: loss @ bf16 precision; bf16 reader: h
    }
}

extern "C" void kernel_launch(void* const* d_in, const int* in_sizes, int n_in,
                              void* d_out, int out_size, void* d_ws, size_t ws_size,
                              hipStream_t stream)
{
    const float* feats = (const float*)d_in[0];
    unsigned int* out = (unsigned int*)d_out;
    char* ws = (char*)d_ws;
    unsigned char* bfA = (unsigned char*)(ws);
    unsigned char* bfB = (unsigned char*)(ws + OFF_B);
    float* sq     = (float*)(ws + OFF_SQ);
    float* U      = (float*)(ws + OFF_U);
    float* V      = (float*)(ws + OFF_V);
    float* alignP = (float*)(ws + OFF_AL);

    prep_kernel<<<1024, 256, 0, stream>>>(feats, bfA, bfB, sq, U, V, alignP);
    band_kernel<<<NBLK, 256, 0, stream>>>(bfA, bfB, sq, U, V);
    tail_kernel<<<1, 1024, 0, stream>>>(U, V, alignP, out);
}